// Round 5
// baseline (138.207 us; speedup 1.0000x reference)
//
#include <hip/hip_runtime.h>
#include <hip/hip_fp16.h>
#include <math.h>

namespace {
constexpr int kN = 16, kC = 64, kH = 224, kW = 224;
constexpr int kOH = kH / 2, kOW = kW / 2;          // 112 x 112
constexpr int PADW = kW + 4;                       // row pad (bank spread)
constexpr int NB_ROWS = 22;                        // circular lo/hi row window
constexpr int kGrid = kN * kC * 2;                 // 2048 (multiple of 8)
constexpr int kChunk = kGrid / 8;                  // 256 blocks per XCD
constexpr float kMagBias = 0.01f;
constexpr float kMB2 = kMagBias * kMagBias;
constexpr float kSqrtHalf = 0.70710678118654752f;
}  // namespace

typedef float v2f __attribute__((ext_vector_type(2)));

__device__ __forceinline__ float magf(float re, float im) {
    return __builtin_amdgcn_sqrtf(fmaf(re, re, fmaf(im, im, kMB2))) - kMagBias;
}

__device__ __forceinline__ void unpack2(unsigned u, float& a, float& b) {
    const __half2 h = __builtin_bit_cast(__half2, u);
    a = __low2float(h);
    b = __high2float(h);
}

__device__ __forceinline__ void nt_store2(float* p, float a, float b) {
    v2f v; v.x = a; v.y = b;
    __builtin_nontemporal_store(v, reinterpret_cast<v2f*>(p));
}

struct Acc {
    float lh_a, lh_b, lh_c, lh_d;
    float hh_a, hh_b, hh_c, hh_d;
    float ll_a, ll_b, ll_c, ll_d;
    float hl_a, hl_b, hl_c, hl_d;
};

__device__ __forceinline__ void acc_init(Acc& A) {
    A.lh_a = A.lh_b = A.lh_c = A.lh_d = 0.f;
    A.hh_a = A.hh_b = A.hh_c = A.hh_d = 0.f;
    A.ll_a = A.ll_b = A.ll_c = A.ll_d = 0.f;
    A.hl_a = A.hl_b = A.hl_c = A.hl_d = 0.f;
}

// One window-row step; k is a compile-time unroll index so the guards fold.
__device__ __forceinline__ void acc_step(Acc& A, int k, float lo0, float hi0,
                                         float lo1, float hi1,
                                         const float* __restrict__ h0,
                                         const float* __restrict__ h1) {
    if (k <= 6) {                 // 7-tap, even output row (taps h1[k])
        A.lh_a = fmaf(h1[k], lo0, A.lh_a);
        A.lh_b = fmaf(h1[k], lo1, A.lh_b);
        A.hh_a = fmaf(h1[k], hi0, A.hh_a);
        A.hh_b = fmaf(h1[k], hi1, A.hh_b);
    }
    if (k >= 1) {                 // 7-tap, odd output row (taps h1[k-1])
        A.lh_c = fmaf(h1[k - 1], lo0, A.lh_c);
        A.lh_d = fmaf(h1[k - 1], lo1, A.lh_d);
        A.hh_c = fmaf(h1[k - 1], hi0, A.hh_c);
        A.hh_d = fmaf(h1[k - 1], hi1, A.hh_d);
    }
    if (k >= 1 && k <= 5) {       // 5-tap, even output row (taps h0[k-1])
        A.ll_a = fmaf(h0[k - 1], lo0, A.ll_a);
        A.ll_b = fmaf(h0[k - 1], lo1, A.ll_b);
        A.hl_a = fmaf(h0[k - 1], hi0, A.hl_a);
        A.hl_b = fmaf(h0[k - 1], hi1, A.hl_b);
    }
    if (k >= 2 && k <= 6) {       // 5-tap, odd output row (taps h0[k-2])
        A.ll_c = fmaf(h0[k - 2], lo0, A.ll_c);
        A.ll_d = fmaf(h0[k - 2], lo1, A.ll_d);
        A.hl_c = fmaf(h0[k - 2], hi0, A.hl_c);
        A.hl_d = fmaf(h0[k - 2], hi1, A.hl_d);
    }
}

__global__ __launch_bounds__(256, 8)
void scat_persist_kernel(const float* __restrict__ x, float* __restrict__ out) {
    // Circular window of horizontal filter outputs, packed fp16 {lo, hi}.
    // 22*228*4 = 20,064 B -> rounds to 20 KiB -> 8 blocks/CU.
    __shared__ __half2 sLH[NB_ROWS][PADW];

    // XCD-aware bijective swizzle: each XCD owns 256 contiguous logical blocks
    // (=128 channels); the two halves of a channel are adjacent -> their 6-row
    // boundary halo overlaps in that XCD's L2.
    const int phys = blockIdx.x;
    const int l    = (phys & 7) * kChunk + (phys >> 3);
    const int ch   = l >> 1;                       // n*kC + c
    const int hh   = l & 1;                        // half: output rows [hh*56, hh*56+56)
    const int tid  = threadIdx.x;

    const float h0[5] = {-0.05f, 0.25f, 0.6f, 0.25f, -0.05f};
    const float h1[7] = {-0.0107142857142857f, 0.0535714285714286f,
                          0.2607142857142857f, -0.6071428571428571f,
                          0.2607142857142857f, 0.0535714285714286f,
                         -0.0107142857142857f};

    const float* __restrict__ xp = x + (size_t)ch * (kH * kW);

    const int n = ch / kC;
    const int c = ch - n * kC;
    const size_t plane   = (size_t)kOH * kOW;      // 12544
    const size_t ostride = (size_t)kC * plane;     // orientation stride
    float* __restrict__ outp = out + ((size_t)n * 7 * kC + c) * plane;
    const int orow0 = hh * 56;                     // first output row of this half

    // 7 bands of 8 output rows; window advances 16 image rows per band.
    for (int t = 0; t < 7; ++t) {
        const int base = (16 * t) % NB_ROWS;       // slot of window row w=0
        const int wlo  = (t == 0) ? 0 : 6;         // new rows: w in [wlo, 22)
        const int nnew = NB_ROWS - wlo;
        const int r0   = hh * 112 + 16 * t - 3;    // image row of w=0

        // ---- Phase 1: horizontal lo/hi for the NEW rows -> circular LDS ----
        for (int task = tid; task < nnew * 56; task += 256) {
            const int s  = task / 56;
            const int cg = task - s * 56;
            const int w  = wlo + s;
            int slot = base + w;
            if (slot >= NB_ROWS) slot -= NB_ROWS;
            int r = r0 + w;
            r = (r < 0) ? (-1 - r) : ((r > kH - 1) ? (2 * kH - 1 - r) : r);
            const float* __restrict__ rowp = xp + r * kW;
            const int c0 = cg * 4;

            float xv[10];  // input cols c0-3 .. c0+6
            if (cg >= 1 && cg <= 54) {
                const float4 A  = *reinterpret_cast<const float4*>(rowp + c0 - 4);
                const float4 B  = *reinterpret_cast<const float4*>(rowp + c0);
                const float4 Cv = *reinterpret_cast<const float4*>(rowp + c0 + 4);
                xv[0] = A.y;  xv[1] = A.z;  xv[2] = A.w;
                xv[3] = B.x;  xv[4] = B.y;  xv[5] = B.z;  xv[6] = B.w;
                xv[7] = Cv.x; xv[8] = Cv.y; xv[9] = Cv.z;
            } else {
                #pragma unroll
                for (int k = 0; k < 10; ++k) {
                    int cc = c0 - 3 + k;
                    cc = (cc < 0) ? (-1 - cc) : ((cc > kW - 1) ? (2 * kW - 1 - cc) : cc);
                    xv[k] = rowp[cc];
                }
            }

            unsigned int pk[4];
            #pragma unroll
            for (int u = 0; u < 4; ++u) {
                const float lo = h0[0] * xv[u + 1] + h0[1] * xv[u + 2] + h0[2] * xv[u + 3]
                               + h0[3] * xv[u + 4] + h0[4] * xv[u + 5];
                const float hi = h1[0] * xv[u + 0] + h1[1] * xv[u + 1] + h1[2] * xv[u + 2]
                               + h1[3] * xv[u + 3] + h1[4] * xv[u + 4] + h1[5] * xv[u + 5]
                               + h1[6] * xv[u + 6];
                __half2 p = __floats2half2_rn(lo, hi);
                pk[u] = __builtin_bit_cast(unsigned int, p);
            }
            *reinterpret_cast<uint4*>(&sLH[slot][c0]) =
                make_uint4(pk[0], pk[1], pk[2], pk[3]);
        }
        __syncthreads();

        // ---- Phase 2: 8 output rows x 56 pixel-pairs ----
        const int i0 = orow0 + 8 * t;
        for (int task = tid; task < 8 * 56; task += 256) {
            const int ii = task / 56;              // 0..7
            const int jp = task - ii * 56;         // pixel pair: j0=2jp, j1=2jp+1

            int b2 = base + 2 * ii;                // slot of window row w=2*ii
            if (b2 >= NB_ROWS) b2 -= NB_ROWS;

            Acc A0, A1;
            acc_init(A0);
            acc_init(A1);

            #pragma unroll
            for (int k = 0; k < 8; ++k) {
                int sl = b2 + k;
                if (sl >= NB_ROWS) sl -= NB_ROWS;
                const uint4 w4 = *reinterpret_cast<const uint4*>(&sLH[sl][4 * jp]);
                float lo00, hi00, lo01, hi01, lo10, hi10, lo11, hi11;
                unpack2(w4.x, lo00, hi00);         // col 4jp   (pixel0 even col)
                unpack2(w4.y, lo01, hi01);         // col 4jp+1 (pixel0 odd col)
                unpack2(w4.z, lo10, hi10);         // col 4jp+2 (pixel1 even col)
                unpack2(w4.w, lo11, hi11);         // col 4jp+3 (pixel1 odd col)
                acc_step(A0, k, lo00, hi00, lo01, hi01, h0, h1);
                acc_step(A1, k, lo10, hi10, lo11, hi11, h0, h1);
            }

            const float llp0 = fmaxf(fmaxf(A0.ll_a, A0.ll_b), fmaxf(A0.ll_c, A0.ll_d));
            const float llp1 = fmaxf(fmaxf(A1.ll_a, A1.ll_b), fmaxf(A1.ll_c, A1.ll_d));

            const float m15_0  = magf((A0.lh_a - A0.lh_d) * kSqrtHalf, (A0.lh_b + A0.lh_c) * kSqrtHalf);
            const float m165_0 = magf((A0.lh_a + A0.lh_d) * kSqrtHalf, (A0.lh_b - A0.lh_c) * kSqrtHalf);
            const float m45_0  = magf((A0.hh_a - A0.hh_d) * kSqrtHalf, (A0.hh_b + A0.hh_c) * kSqrtHalf);
            const float m135_0 = magf((A0.hh_a + A0.hh_d) * kSqrtHalf, (A0.hh_b - A0.hh_c) * kSqrtHalf);
            const float m75_0  = magf((A0.hl_a - A0.hl_d) * kSqrtHalf, (A0.hl_b + A0.hl_c) * kSqrtHalf);
            const float m105_0 = magf((A0.hl_a + A0.hl_d) * kSqrtHalf, (A0.hl_b - A0.hl_c) * kSqrtHalf);

            const float m15_1  = magf((A1.lh_a - A1.lh_d) * kSqrtHalf, (A1.lh_b + A1.lh_c) * kSqrtHalf);
            const float m165_1 = magf((A1.lh_a + A1.lh_d) * kSqrtHalf, (A1.lh_b - A1.lh_c) * kSqrtHalf);
            const float m45_1  = magf((A1.hh_a - A1.hh_d) * kSqrtHalf, (A1.hh_b + A1.hh_c) * kSqrtHalf);
            const float m135_1 = magf((A1.hh_a + A1.hh_d) * kSqrtHalf, (A1.hh_b - A1.hh_c) * kSqrtHalf);
            const float m75_1  = magf((A1.hl_a - A1.hl_d) * kSqrtHalf, (A1.hl_b + A1.hl_c) * kSqrtHalf);
            const float m105_1 = magf((A1.hl_a + A1.hl_d) * kSqrtHalf, (A1.hl_b - A1.hl_c) * kSqrtHalf);

            const size_t pix = (size_t)(i0 + ii) * kOW + 2 * jp;
            nt_store2(outp + pix,               llp0,   llp1);
            nt_store2(outp + ostride     + pix, m15_0,  m15_1);
            nt_store2(outp + 2 * ostride + pix, m45_0,  m45_1);
            nt_store2(outp + 3 * ostride + pix, m75_0,  m75_1);
            nt_store2(outp + 4 * ostride + pix, m105_0, m105_1);
            nt_store2(outp + 5 * ostride + pix, m135_0, m135_1);
            nt_store2(outp + 6 * ostride + pix, m165_0, m165_1);
        }
        __syncthreads();   // protect slots phase1(t+1) will overwrite
    }
}

extern "C" void kernel_launch(void* const* d_in, const int* in_sizes, int n_in,
                              void* d_out, int out_size, void* d_ws, size_t ws_size,
                              hipStream_t stream) {
    const float* x = (const float*)d_in[0];
    float* out = (float*)d_out;
    scat_persist_kernel<<<kGrid, 256, 0, stream>>>(x, out);
}